// Round 4
// baseline (424.485 us; speedup 1.0000x reference)
//
#include <hip/hip_runtime.h>

// LSTM_61203283968689 — R10: per-gate MFMA/trans interleave enforced with
// sched_barrier(0) fences (SGB groups removed — R9 showed they mis-bin TRANS
// ops and regressed 6%). R7/R9 counters: MfmaUtil ~44 + VALUBusy ~43, sum ~87%
// -> matrix and VALU/trans pipes mutually exclusive. Model: compiler clusters
// all 12-16 MFMAs before ew; MFMA issue is backpressured by the matrix pipe,
// so each wave reaches its trans chain only after the full 3-wave 854cy drain;
// then all ew bursts run with the matrix pipe idle (tick = 750+740+gap = 1600cy).
// R10 steady tick emits, per gate g: [self-MFMA x2][input-MFMA (next step)]
// [sigm(g)] with a full scheduling fence between gates, so trans issue starts
// ~120cy into the drain and the other waves' MFMAs fill the pipe during each
// wave's trans burst. All ds_reads + lgkm waits stay in the first region
// (fences see register-only code -> no waitcnt fragmentation, m141 hazard n/a).
// Accumulation order per gate unchanged (bias, ih-lo, ih-hi, hh-lo, hh-hi)
// -> bit-identical output. Edge ticks (9/516) keep the R7 body. Layout,
// staging, 82 KiB LDS -> 1 block/CU, diagonal L0@t/L1@t+2/L2@t+4 as R7.

#define TT   512
#define NTH  768
#define NBLK 256

typedef _Float16 h16;
typedef __attribute__((ext_vector_type(8))) _Float16 h16x8;
typedef __attribute__((ext_vector_type(4))) float f32x4;

#define MFMA16(a, b, c) __builtin_amdgcn_mfma_f32_16x16x32_f16((a), (b), (c), 0, 0, 0)
#define FENCE() __builtin_amdgcn_sched_barrier(0)

__device__ __forceinline__ float sigm(float z) {
    return __builtin_amdgcn_rcpf(1.f + __expf(-z));
}

// B-fragment: 8 consecutive k of row `ro` from row-major W[.,ld], f32 -> f16.
__device__ __forceinline__ h16x8 loadB(const float* __restrict__ W, int ld, int ro,
                                       int k0, int kmax) {
    h16x8 r;
    #pragma unroll
    for (int i = 0; i < 8; ++i) {
        const int k = k0 + i;
        r[i] = (h16)((k < kmax) ? W[(size_t)ro * ld + k] : 0.f);
    }
    return r;
}

__global__ __attribute__((amdgpu_flat_work_group_size(NTH, NTH), amdgpu_waves_per_eu(3)))
void lstm_mfma(
    const float* __restrict__ x,
    const float* __restrict__ wih0, const float* __restrict__ whh0,
    const float* __restrict__ bih0, const float* __restrict__ bhh0,
    const float* __restrict__ wih1, const float* __restrict__ whh1,
    const float* __restrict__ bih1, const float* __restrict__ bhh1,
    const float* __restrict__ wih2, const float* __restrict__ whh2,
    const float* __restrict__ bih2, const float* __restrict__ bhh2,
    const float* __restrict__ wfc, const float* __restrict__ bfc,
    float* __restrict__ out)
{
    const int tid  = threadIdx.x;
    const int w    = tid >> 6;        // wave 0..11
    const int wl   = w >> 2;          // layer 0..2
    const int wg   = w & 3;           // gate-tile group: units [16wg, 16wg+16)
    const int lane = tid & 63;
    const int nloc = lane & 15;       // unit-local index / B-frag col
    const int kg   = lane >> 4;       // k-group 0..3 ; also sample (C-row 4*kg)
    const int b4   = blockIdx.x * 4;
    const int u    = wg * 16 + nloc;  // this lane's hidden unit

    // LDS: XL 64 KiB + HT 12 KiB + PAD 6 KiB = 82 KiB -> exactly 1 block/CU
    __shared__ alignas(16) h16 XL[2 * 32 * 512];   // x, 2 chunks x 32 t x frag-tile(512)
    __shared__ alignas(16) h16 HT[3 * 2 * 1024];   // h[layer][pp] frag-tiles
    __shared__ h16 PAD[3072];                      // occupancy limiter (kept alive below)

    // ---------------- B fragments for THIS wave's layer only ----------------
    h16x8 Bf[4][4];
    float bias[4];
    #pragma unroll
    for (int g = 0; g < 4; ++g) {
        const int ro = g * 64 + u;                  // original row (i,f,g,o blocks)
        if (wl == 0) {
            Bf[g][0] = loadB(wih0, 22, ro, kg * 8,      22);
            Bf[g][1] = loadB(whh0, 64, ro, kg * 8,      64);
            Bf[g][2] = loadB(whh0, 64, ro, 32 + kg * 8, 64);
            Bf[g][3] = Bf[g][2];
            bias[g]  = bih0[ro] + bhh0[ro];
        } else if (wl == 1) {
            Bf[g][0] = loadB(wih1, 64, ro, kg * 8,      64);
            Bf[g][1] = loadB(wih1, 64, ro, 32 + kg * 8, 64);
            Bf[g][2] = loadB(whh1, 64, ro, kg * 8,      64);
            Bf[g][3] = loadB(whh1, 64, ro, 32 + kg * 8, 64);
            bias[g]  = bih1[ro] + bhh1[ro];
        } else {
            Bf[g][0] = loadB(wih2, 64, ro, kg * 8,      64);
            Bf[g][1] = loadB(wih2, 64, ro, 32 + kg * 8, 64);
            Bf[g][2] = loadB(whh2, 64, ro, kg * 8,      64);
            Bf[g][3] = loadB(whh2, 64, ro, 32 + kg * 8, 64);
            bias[g]  = bih2[ro] + bhh2[ro];
        }
    }

    // keep PAD alive (condition can never be true at runtime)
    if (bias[0] > 1.0e30f) { PAD[tid & 2047] = (h16)bias[0]; out[0] = (float)PAD[0]; }

    // ---------------- zero LDS (pad rows must stay zero) ----------------
    {
        int* xz = (int*)XL;
        for (int i = tid; i < 2 * 32 * 256; i += NTH) xz[i] = 0;
        int* hz = (int*)HT;
        for (int i = tid; i < 3 * 2 * 512; i += NTH) hz[i] = 0;
    }
    __syncthreads();

    // ---------------- x staging: sample bl -> A-row 4*bl, frag layout ------------
    auto stage_x = [&](int chunk) {
        if (tid < 4 * 22) {
            const int bl = tid / 22, ii = tid - bl * 22;
            const float* src = x + (size_t)(b4 + bl) * (22 * 512) + (size_t)ii * 512
                                 + chunk * 32;
            h16* dst = &XL[(chunk & 1) * (32 * 512) + (ii >> 3) * 128 + (4 * bl) * 8 + (ii & 7)];
            #pragma unroll
            for (int q = 0; q < 8; ++q) {
                const float4 v = ((const float4*)src)[q];
                dst[(q * 4 + 0) * 512] = (h16)v.x;
                dst[(q * 4 + 1) * 512] = (h16)v.y;
                dst[(q * 4 + 2) * 512] = (h16)v.z;
                dst[(q * 4 + 3) * 512] = (h16)v.w;
            }
        }
    };
    stage_x(0);

    // ---------------- per-lane constants ----------------
    const int lo8  = lane * 8;                           // A-frag offset (h16 units)
    const int hoff = (u >> 3) * 128 + kg * 32 + (u & 7); // h-write: row 4*kg, unit u

    float cst = 0.f;

    auto ew = [&](const f32x4& zi, const f32x4& zf, const f32x4& zg, const f32x4& zo,
                  h16* hb) {
        const float vi = sigm(zi[0]);
        const float vf = sigm(zf[0]);
        const float vg = 2.f * sigm(2.f * zg[0]) - 1.f;
        const float vo = sigm(zo[0]);
        const float c  = vf * cst + vi * vg;
        cst = c;
        hb[hoff] = (h16)(vo * (2.f * sigm(2.f * c) - 1.f));
    };

    // gate-bias C fragments (read-only; MFMA C-in by value, so zero movs/tick)
    f32x4 zb[4];
    #pragma unroll
    for (int g = 0; g < 4; ++g) zb[g] = f32x4{bias[g], 0.f, 0.f, 0.f};

    __syncthreads();

    // ---- prologue: zc carries bias + input-half contribution of the NEXT step ----
    f32x4 zc[4];
    if (wl == 0) {
        const h16x8 ax0 = *(const h16x8*)&XL[lo8];   // chunk 0, t=0
        #pragma unroll
        for (int g = 0; g < 4; ++g) zc[g] = MFMA16(ax0, Bf[g][0], zb[g]);
    } else {
        #pragma unroll
        for (int g = 0; g < 4; ++g) zc[g] = zb[g];
    }

    // ===================== EDGE tick (R7 body, used 9/516 ticks) =====================
    auto tick_edge = [&](int t) {
        const int wb = t & 1, rb = wb ^ 1;
        const h16* h0r = HT + 0 * 2048 + rb * 1024;
        h16*       h0w = HT + 0 * 2048 + wb * 1024;
        const h16* h1r = HT + 1 * 2048 + rb * 1024;
        h16*       h1w = HT + 1 * 2048 + wb * 1024;
        const h16* h2r = HT + 2 * 2048 + rb * 1024;
        h16*       h2w = HT + 2 * 2048 + wb * 1024;

        if (wl == 0) {
            const bool sa = (t < TT);
            const bool ia = (t < TT - 1);
            f32x4 z[4];
            h16x8 a0lo, a0hi, axn;
            if (sa) {
                a0lo = *(const h16x8*)(h0r + lo8);
                a0hi = *(const h16x8*)(h0r + lo8 + 512);
            }
            if (ia) {
                const int tn = t + 1;
                axn = *(const h16x8*)&XL[((tn >> 5) & 1) * (32 * 512) + (tn & 31) * 512 + lo8];
            }
            if (sa) {
                #pragma unroll
                for (int g = 0; g < 4; ++g) {
                    z[g] = MFMA16(a0lo, Bf[g][1], zc[g]);
                    z[g] = MFMA16(a0hi, Bf[g][2], z[g]);
                }
            }
            if ((t & 31) == 16 && (t >> 5) < 15) stage_x((t >> 5) + 1);
            if (sa) ew(z[0], z[1], z[2], z[3], h0w);
            if (ia) {
                #pragma unroll
                for (int g = 0; g < 4; ++g)
                    zc[g] = MFMA16(axn, Bf[g][0], zb[g]);
            }
        } else if (wl == 1) {
            const bool sa = (t >= 2 && t < TT + 2);
            const bool ia = (t >= 1 && t < TT + 1);
            f32x4 z[4];
            h16x8 a1lo, a1hi, a0lo, a0hi;
            if (sa) {
                a1lo = *(const h16x8*)(h1r + lo8);
                a1hi = *(const h16x8*)(h1r + lo8 + 512);
            }
            if (ia) {
                a0lo = *(const h16x8*)(h0r + lo8);
                a0hi = *(const h16x8*)(h0r + lo8 + 512);
            }
            if (sa) {
                #pragma unroll
                for (int g = 0; g < 4; ++g) {
                    z[g] = MFMA16(a1lo, Bf[g][2], zc[g]);
                    z[g] = MFMA16(a1hi, Bf[g][3], z[g]);
                }
            }
            if (sa) ew(z[0], z[1], z[2], z[3], h1w);
            if (ia) {
                #pragma unroll
                for (int g = 0; g < 4; ++g) {
                    f32x4 zn = MFMA16(a0lo, Bf[g][0], zb[g]);
                    zc[g] = MFMA16(a0hi, Bf[g][1], zn);
                }
            }
        } else {
            const bool sa = (t >= 4);
            const bool ia = (t >= 3 && t < TT + 3);
            f32x4 z[4];
            h16x8 a2lo, a2hi, a1lo, a1hi;
            if (sa) {
                a2lo = *(const h16x8*)(h2r + lo8);
                a2hi = *(const h16x8*)(h2r + lo8 + 512);
            }
            if (ia) {
                a1lo = *(const h16x8*)(h1r + lo8);
                a1hi = *(const h16x8*)(h1r + lo8 + 512);
            }
            if (sa) {
                #pragma unroll
                for (int g = 0; g < 4; ++g) {
                    z[g] = MFMA16(a2lo, Bf[g][2], zc[g]);
                    z[g] = MFMA16(a2hi, Bf[g][3], z[g]);
                }
            }
            if (sa) ew(z[0], z[1], z[2], z[3], h2w);
            if (ia) {
                #pragma unroll
                for (int g = 0; g < 4; ++g) {
                    f32x4 zn = MFMA16(a1lo, Bf[g][0], zb[g]);
                    zc[g] = MFMA16(a1hi, Bf[g][1], zn);
                }
            }
        }
        __syncthreads();
    };

    // ===== STEADY tick: per-gate [MFMAs][sigm] regions pinned by sched_barrier(0) =====
    // All ds_reads (and their lgkm waits) live in region 0; regions 1..4 are
    // register-only {3-4 MFMA + 1 sigm} blocks; region 5 is the c/h tail + write.
    // Emitted order per wave alternates MFMA/trans every ~4 ops, so each wave's
    // trans burst overlaps the OTHER waves' MFMA drain instead of following it.
    auto tick_steady = [&](int t) {
        const int wb = t & 1, rb = wb ^ 1;
        const h16* h0r = HT + 0 * 2048 + rb * 1024;
        h16*       h0w = HT + 0 * 2048 + wb * 1024;
        const h16* h1r = HT + 1 * 2048 + rb * 1024;
        h16*       h1w = HT + 1 * 2048 + wb * 1024;
        const h16* h2r = HT + 2 * 2048 + rb * 1024;
        h16*       h2w = HT + 2 * 2048 + wb * 1024;

        if (wl == 0) {           // ---- L0: self step t, input-prefetch x(t+1) ----
            const h16x8 a0lo = *(const h16x8*)(h0r + lo8);
            const h16x8 a0hi = *(const h16x8*)(h0r + lo8 + 512);
            const int tn = t + 1;
            const h16x8 axn  = *(const h16x8*)&XL[((tn >> 5) & 1) * (32 * 512)
                                                  + (tn & 31) * 512 + lo8];
            FENCE();
            f32x4 z0 = MFMA16(a0lo, Bf[0][1], zc[0]); z0 = MFMA16(a0hi, Bf[0][2], z0);
            zc[0] = MFMA16(axn, Bf[0][0], zb[0]);
            const float vi = sigm(z0[0]);
            FENCE();
            f32x4 z1 = MFMA16(a0lo, Bf[1][1], zc[1]); z1 = MFMA16(a0hi, Bf[1][2], z1);
            zc[1] = MFMA16(axn, Bf[1][0], zb[1]);
            const float vf = sigm(z1[0]);
            FENCE();
            f32x4 z2 = MFMA16(a0lo, Bf[2][1], zc[2]); z2 = MFMA16(a0hi, Bf[2][2], z2);
            zc[2] = MFMA16(axn, Bf[2][0], zb[2]);
            const float vg = 2.f * sigm(2.f * z2[0]) - 1.f;
            FENCE();
            f32x4 z3 = MFMA16(a0lo, Bf[3][1], zc[3]); z3 = MFMA16(a0hi, Bf[3][2], z3);
            zc[3] = MFMA16(axn, Bf[3][0], zb[3]);
            const float vo = sigm(z3[0]);
            FENCE();
            const float c  = vf * cst + vi * vg;
            cst = c;
            h0w[hoff] = (h16)(vo * (2.f * sigm(2.f * c) - 1.f));
            if ((t & 31) == 16 && (t >> 5) < 15) stage_x((t >> 5) + 1);
        } else if (wl == 1) {    // ---- L1: self step t-2, input-prefetch t-1 ----
            const h16x8 a1lo = *(const h16x8*)(h1r + lo8);
            const h16x8 a1hi = *(const h16x8*)(h1r + lo8 + 512);
            const h16x8 a0lo = *(const h16x8*)(h0r + lo8);
            const h16x8 a0hi = *(const h16x8*)(h0r + lo8 + 512);
            FENCE();
            f32x4 z0 = MFMA16(a1lo, Bf[0][2], zc[0]); z0 = MFMA16(a1hi, Bf[0][3], z0);
            { f32x4 zn = MFMA16(a0lo, Bf[0][0], zb[0]); zc[0] = MFMA16(a0hi, Bf[0][1], zn); }
            const float vi = sigm(z0[0]);
            FENCE();
            f32x4 z1 = MFMA16(a1lo, Bf[1][2], zc[1]); z1 = MFMA16(a1hi, Bf[1][3], z1);
            { f32x4 zn = MFMA16(a0lo, Bf[1][0], zb[1]); zc[1] = MFMA16(a0hi, Bf[1][1], zn); }
            const float vf = sigm(z1[0]);
            FENCE();
            f32x4 z2 = MFMA16(a1lo, Bf[2][2], zc[2]); z2 = MFMA16(a1hi, Bf[2][3], z2);
            { f32x4 zn = MFMA16(a0lo, Bf[2][0], zb[2]); zc[2] = MFMA16(a0hi, Bf[2][1], zn); }
            const float vg = 2.f * sigm(2.f * z2[0]) - 1.f;
            FENCE();
            f32x4 z3 = MFMA16(a1lo, Bf[3][2], zc[3]); z3 = MFMA16(a1hi, Bf[3][3], z3);
            { f32x4 zn = MFMA16(a0lo, Bf[3][0], zb[3]); zc[3] = MFMA16(a0hi, Bf[3][1], zn); }
            const float vo = sigm(z3[0]);
            FENCE();
            const float c  = vf * cst + vi * vg;
            cst = c;
            h1w[hoff] = (h16)(vo * (2.f * sigm(2.f * c) - 1.f));
        } else {                 // ---- L2: self step t-4, input-prefetch t-3 ----
            const h16x8 a2lo = *(const h16x8*)(h2r + lo8);
            const h16x8 a2hi = *(const h16x8*)(h2r + lo8 + 512);
            const h16x8 a1lo = *(const h16x8*)(h1r + lo8);
            const h16x8 a1hi = *(const h16x8*)(h1r + lo8 + 512);
            FENCE();
            f32x4 z0 = MFMA16(a2lo, Bf[0][2], zc[0]); z0 = MFMA16(a2hi, Bf[0][3], z0);
            { f32x4 zn = MFMA16(a1lo, Bf[0][0], zb[0]); zc[0] = MFMA16(a1hi, Bf[0][1], zn); }
            const float vi = sigm(z0[0]);
            FENCE();
            f32x4 z1 = MFMA16(a2lo, Bf[1][2], zc[1]); z1 = MFMA16(a2hi, Bf[1][3], z1);
            { f32x4 zn = MFMA16(a1lo, Bf[1][0], zb[1]); zc[1] = MFMA16(a1hi, Bf[1][1], zn); }
            const float vf = sigm(z1[0]);
            FENCE();
            f32x4 z2 = MFMA16(a2lo, Bf[2][2], zc[2]); z2 = MFMA16(a2hi, Bf[2][3], z2);
            { f32x4 zn = MFMA16(a1lo, Bf[2][0], zb[2]); zc[2] = MFMA16(a1hi, Bf[2][1], zn); }
            const float vg = 2.f * sigm(2.f * z2[0]) - 1.f;
            FENCE();
            f32x4 z3 = MFMA16(a2lo, Bf[3][2], zc[3]); z3 = MFMA16(a2hi, Bf[3][3], z3);
            { f32x4 zn = MFMA16(a1lo, Bf[3][0], zb[3]); zc[3] = MFMA16(a1hi, Bf[3][1], zn); }
            const float vo = sigm(z3[0]);
            FENCE();
            const float c  = vf * cst + vi * vg;
            cst = c;
            h2w[hoff] = (h16)(vo * (2.f * sigm(2.f * c) - 1.f));
        }
        __syncthreads();
    };

    #pragma unroll 1
    for (int t = 0; t < 4; ++t) tick_edge(t);
    #pragma unroll 1
    for (int t = 4; t < TT - 1; ++t) tick_steady(t);        // branch-free steady state
    #pragma unroll 1
    for (int t = TT - 1; t < TT + 4; ++t) tick_edge(t);

    // ------------- FC epilogue: h2(step 511) written at tick 515 -> buffer 1 ------
    if (tid < 16) {
        const int ms = tid >> 2, o = tid & 3;
        const h16* h2 = HT + 2 * 2048 + 1024;
        float acc = bfc[o];
        #pragma unroll 1
        for (int uu = 0; uu < 64; ++uu)
            acc += (float)h2[(uu >> 3) * 128 + (4 * ms) * 8 + (uu & 7)] * wfc[o * 64 + uu];
        out[(b4 + ms) * 4 + o] = acc;
    }
}

extern "C" void kernel_launch(void* const* d_in, const int* in_sizes, int n_in,
                              void* d_out, int out_size, void* d_ws, size_t ws_size,
                              hipStream_t stream) {
    const float* x    = (const float*)d_in[0];
    const float* wih0 = (const float*)d_in[1];
    const float* whh0 = (const float*)d_in[2];
    const float* bih0 = (const float*)d_in[3];
    const float* bhh0 = (const float*)d_in[4];
    const float* wih1 = (const float*)d_in[5];
    const float* whh1 = (const float*)d_in[6];
    const float* bih1 = (const float*)d_in[7];
    const float* bhh1 = (const float*)d_in[8];
    const float* wih2 = (const float*)d_in[9];
    const float* whh2 = (const float*)d_in[10];
    const float* bih2 = (const float*)d_in[11];
    const float* bhh2 = (const float*)d_in[12];
    const float* wfc  = (const float*)d_in[13];
    const float* bfc  = (const float*)d_in[14];
    float* out = (float*)d_out;

    lstm_mfma<<<dim3(NBLK), dim3(NTH), 0, stream>>>(
        x, wih0, whh0, bih0, bhh0, wih1, whh1, bih1, bhh1,
        wih2, whh2, bih2, bhh2, wfc, bfc, out);
}

// Round 6
// 398.951 us; speedup vs baseline: 1.0640x; 1.0640x over previous
//
#include <hip/hip_runtime.h>

// LSTM_61203283968689 — R12 (= R11 resubmit; round 5 died to infra container
// failure — same failure mode as round 2, whose identical resubmit ran fine).
// Exact R7 body (best measured: 344 µs) + static per-layer wave priority.
// R9 (SGB) and R10 (sched_barrier fences) proved source-order interleave is
// NOT the lever: MfmaUtil+VALUBusy stayed ~87% serialized at any emission
// order. Model: the 3 waves/SIMD (one per layer) are barrier-phase-locked and
// the issue arbiter is fair, so they run in lockstep and alternate all-MFMA /
// all-trans windows together — each pipe idles while the other runs
// (tick = 750 + 750 + gap). R12 sets static priorities L0=2, L1=1, L2=0 once:
// the arbiter drains L0's MFMAs first, so L0's trans burst overlaps L1's MFMA
// drain, L1's overlaps L2's. Target tick ~= 750 + ~230 ~= 1050 cyc.
// Math/layout/sync identical to R7 -> bit-identical output. No hang risk:
// s_barrier sleeps (not spins), so low-prio waves always reach the barrier.

#define TT   512
#define NTH  768
#define NBLK 256

typedef _Float16 h16;
typedef __attribute__((ext_vector_type(8))) _Float16 h16x8;
typedef __attribute__((ext_vector_type(4))) float f32x4;

#define MFMA16(a, b, c) __builtin_amdgcn_mfma_f32_16x16x32_f16((a), (b), (c), 0, 0, 0)

__device__ __forceinline__ float sigm(float z) {
    return __builtin_amdgcn_rcpf(1.f + __expf(-z));
}

// B-fragment: 8 consecutive k of row `ro` from row-major W[.,ld], f32 -> f16.
__device__ __forceinline__ h16x8 loadB(const float* __restrict__ W, int ld, int ro,
                                       int k0, int kmax) {
    h16x8 r;
    #pragma unroll
    for (int i = 0; i < 8; ++i) {
        const int k = k0 + i;
        r[i] = (h16)((k < kmax) ? W[(size_t)ro * ld + k] : 0.f);
    }
    return r;
}

struct TrueC  { static constexpr bool value = true;  };
struct FalseC { static constexpr bool value = false; };

__global__ __attribute__((amdgpu_flat_work_group_size(NTH, NTH), amdgpu_waves_per_eu(3)))
void lstm_mfma(
    const float* __restrict__ x,
    const float* __restrict__ wih0, const float* __restrict__ whh0,
    const float* __restrict__ bih0, const float* __restrict__ bhh0,
    const float* __restrict__ wih1, const float* __restrict__ whh1,
    const float* __restrict__ bih1, const float* __restrict__ bhh1,
    const float* __restrict__ wih2, const float* __restrict__ whh2,
    const float* __restrict__ bih2, const float* __restrict__ bhh2,
    const float* __restrict__ wfc, const float* __restrict__ bfc,
    float* __restrict__ out)
{
    const int tid  = threadIdx.x;
    const int w    = tid >> 6;        // wave 0..11
    const int wl   = w >> 2;          // layer 0..2
    const int wg   = w & 3;           // gate-tile group: units [16wg, 16wg+16)
    const int lane = tid & 63;
    const int nloc = lane & 15;       // unit-local index / B-frag col
    const int kg   = lane >> 4;       // k-group 0..3 ; also sample (C-row 4*kg)
    const int b4   = blockIdx.x * 4;
    const int u    = wg * 16 + nloc;  // this lane's hidden unit

    // LDS: XL 64 KiB + HT 12 KiB + PAD 6 KiB = 82 KiB -> exactly 1 block/CU
    __shared__ alignas(16) h16 XL[2 * 32 * 512];   // x, 2 chunks x 32 t x frag-tile(512)
    __shared__ alignas(16) h16 HT[3 * 2 * 1024];   // h[layer][pp] frag-tiles
    __shared__ h16 PAD[3072];                      // occupancy limiter (kept alive below)

    // ---------------- B fragments for THIS wave's layer only ----------------
    h16x8 Bf[4][4];
    float bias[4];
    #pragma unroll
    for (int g = 0; g < 4; ++g) {
        const int ro = g * 64 + u;                  // original row (i,f,g,o blocks)
        if (wl == 0) {
            Bf[g][0] = loadB(wih0, 22, ro, kg * 8,      22);
            Bf[g][1] = loadB(whh0, 64, ro, kg * 8,      64);
            Bf[g][2] = loadB(whh0, 64, ro, 32 + kg * 8, 64);
            Bf[g][3] = Bf[g][2];
            bias[g]  = bih0[ro] + bhh0[ro];
        } else if (wl == 1) {
            Bf[g][0] = loadB(wih1, 64, ro, kg * 8,      64);
            Bf[g][1] = loadB(wih1, 64, ro, 32 + kg * 8, 64);
            Bf[g][2] = loadB(whh1, 64, ro, kg * 8,      64);
            Bf[g][3] = loadB(whh1, 64, ro, 32 + kg * 8, 64);
            bias[g]  = bih1[ro] + bhh1[ro];
        } else {
            Bf[g][0] = loadB(wih2, 64, ro, kg * 8,      64);
            Bf[g][1] = loadB(wih2, 64, ro, 32 + kg * 8, 64);
            Bf[g][2] = loadB(whh2, 64, ro, kg * 8,      64);
            Bf[g][3] = loadB(whh2, 64, ro, 32 + kg * 8, 64);
            bias[g]  = bih2[ro] + bhh2[ro];
        }
    }

    // keep PAD alive (condition can never be true at runtime)
    if (bias[0] > 1.0e30f) { PAD[tid & 2047] = (h16)bias[0]; out[0] = (float)PAD[0]; }

    // ---------------- zero LDS (pad rows must stay zero) ----------------
    {
        int* xz = (int*)XL;
        for (int i = tid; i < 2 * 32 * 256; i += NTH) xz[i] = 0;
        int* hz = (int*)HT;
        for (int i = tid; i < 3 * 2 * 512; i += NTH) hz[i] = 0;
    }
    __syncthreads();

    // ---------------- x staging: sample bl -> A-row 4*bl, frag layout ------------
    auto stage_x = [&](int chunk) {
        if (tid < 4 * 22) {
            const int bl = tid / 22, ii = tid - bl * 22;
            const float* src = x + (size_t)(b4 + bl) * (22 * 512) + (size_t)ii * 512
                                 + chunk * 32;
            h16* dst = &XL[(chunk & 1) * (32 * 512) + (ii >> 3) * 128 + (4 * bl) * 8 + (ii & 7)];
            #pragma unroll
            for (int q = 0; q < 8; ++q) {
                const float4 v = ((const float4*)src)[q];
                dst[(q * 4 + 0) * 512] = (h16)v.x;
                dst[(q * 4 + 1) * 512] = (h16)v.y;
                dst[(q * 4 + 2) * 512] = (h16)v.z;
                dst[(q * 4 + 3) * 512] = (h16)v.w;
            }
        }
    };
    stage_x(0);

    // ---------------- per-lane constants ----------------
    const int lo8  = lane * 8;                           // A-frag offset (h16 units)
    const int hoff = (u >> 3) * 128 + kg * 32 + (u & 7); // h-write: row 4*kg, unit u

    float cst = 0.f;

    auto ew = [&](const f32x4& zi, const f32x4& zf, const f32x4& zg, const f32x4& zo,
                  h16* hb) {
        const float vi = sigm(zi[0]);
        const float vf = sigm(zf[0]);
        const float vg = 2.f * sigm(2.f * zg[0]) - 1.f;
        const float vo = sigm(zo[0]);
        const float c  = vf * cst + vi * vg;
        cst = c;
        hb[hoff] = (h16)(vo * (2.f * sigm(2.f * c) - 1.f));
    };

    // gate-bias C fragments (read-only; MFMA C-in by value, so zero movs/tick)
    f32x4 zb[4];
    #pragma unroll
    for (int g = 0; g < 4; ++g) zb[g] = f32x4{bias[g], 0.f, 0.f, 0.f};

    __syncthreads();

    // ---- static per-layer wave priority: break the 3-wave lockstep ----
    // The issue arbiter favors L0, so L0's MFMAs drain first and its trans
    // burst overlaps L1's MFMA drain; L1's overlaps L2's. s_setprio takes an
    // immediate -> wave-uniform branch per layer. Priority is sticky.
    if (wl == 0)      __builtin_amdgcn_s_setprio(2);
    else if (wl == 1) __builtin_amdgcn_s_setprio(1);
    // wl == 2 keeps default priority 0

    // ---- prologue: zc carries bias + input-half contribution of the NEXT step ----
    f32x4 zc[4];
    if (wl == 0) {
        const h16x8 ax0 = *(const h16x8*)&XL[lo8];   // chunk 0, t=0
        #pragma unroll
        for (int g = 0; g < 4; ++g) zc[g] = MFMA16(ax0, Bf[g][0], zb[g]);
    } else {
        #pragma unroll
        for (int g = 0; g < 4; ++g) zc[g] = zb[g];
    }

    // ============================ diagonal tick loop ============================
    auto tick = [&](int t, auto edgec) {
        constexpr bool EDGE = decltype(edgec)::value;
        const int wb = t & 1, rb = wb ^ 1;
        const h16* h0r = HT + 0 * 2048 + rb * 1024;
        h16*       h0w = HT + 0 * 2048 + wb * 1024;
        const h16* h1r = HT + 1 * 2048 + rb * 1024;
        h16*       h1w = HT + 1 * 2048 + wb * 1024;
        const h16* h2r = HT + 2 * 2048 + rb * 1024;
        h16*       h2w = HT + 2 * 2048 + wb * 1024;

        if (wl == 0) {           // -------- L0: self for step t, x-prefetch t+1 ------
            const bool sa = !EDGE || (t < TT);
            const bool ia = !EDGE || (t < TT - 1);
            f32x4 z[4];
            h16x8 a0lo, a0hi, axn;
            if (sa) {
                a0lo = *(const h16x8*)(h0r + lo8);
                a0hi = *(const h16x8*)(h0r + lo8 + 512);
            }
            if (ia) {
                const int tn = t + 1;
                axn = *(const h16x8*)&XL[((tn >> 5) & 1) * (32 * 512) + (tn & 31) * 512 + lo8];
            }
            if (sa) {
                #pragma unroll
                for (int g = 0; g < 4; ++g) {
                    z[g] = MFMA16(a0lo, Bf[g][1], zc[g]);
                    z[g] = MFMA16(a0hi, Bf[g][2], z[g]);
                }
            }
            if ((t & 31) == 16 && (t >> 5) < 15) stage_x((t >> 5) + 1);
            if (sa) ew(z[0], z[1], z[2], z[3], h0w);
            if (ia) {
                #pragma unroll
                for (int g = 0; g < 4; ++g)
                    zc[g] = MFMA16(axn, Bf[g][0], zb[g]);
            }
        } else if (wl == 1) {    // ---- L1: self for step t-2, input-prefetch t-1 ----
            const bool sa = !EDGE || (t >= 2 && t < TT + 2);
            const bool ia = !EDGE || (t >= 1 && t < TT + 1);
            f32x4 z[4];
            h16x8 a1lo, a1hi, a0lo, a0hi;
            if (sa) {
                a1lo = *(const h16x8*)(h1r + lo8);
                a1hi = *(const h16x8*)(h1r + lo8 + 512);
            }
            if (ia) {
                a0lo = *(const h16x8*)(h0r + lo8);
                a0hi = *(const h16x8*)(h0r + lo8 + 512);
            }
            if (sa) {
                #pragma unroll
                for (int g = 0; g < 4; ++g) {
                    z[g] = MFMA16(a1lo, Bf[g][2], zc[g]);
                    z[g] = MFMA16(a1hi, Bf[g][3], z[g]);
                }
            }
            if (sa) ew(z[0], z[1], z[2], z[3], h1w);
            if (ia) {
                #pragma unroll
                for (int g = 0; g < 4; ++g) {
                    f32x4 zn = MFMA16(a0lo, Bf[g][0], zb[g]);
                    zc[g] = MFMA16(a0hi, Bf[g][1], zn);
                }
            }
        } else {                 // ------ L2: self for step t-4, input-prefetch t-3 ------
            const bool sa = !EDGE || (t >= 4);
            const bool ia = !EDGE || (t >= 3 && t < TT + 3);
            f32x4 z[4];
            h16x8 a2lo, a2hi, a1lo, a1hi;
            if (sa) {
                a2lo = *(const h16x8*)(h2r + lo8);
                a2hi = *(const h16x8*)(h2r + lo8 + 512);
            }
            if (ia) {
                a1lo = *(const h16x8*)(h1r + lo8);
                a1hi = *(const h16x8*)(h1r + lo8 + 512);
            }
            if (sa) {
                #pragma unroll
                for (int g = 0; g < 4; ++g) {
                    z[g] = MFMA16(a2lo, Bf[g][2], zc[g]);
                    z[g] = MFMA16(a2hi, Bf[g][3], z[g]);
                }
            }
            if (sa) ew(z[0], z[1], z[2], z[3], h2w);
            if (ia) {
                #pragma unroll
                for (int g = 0; g < 4; ++g) {
                    f32x4 zn = MFMA16(a1lo, Bf[g][0], zb[g]);
                    zc[g] = MFMA16(a1hi, Bf[g][1], zn);
                }
            }
        }

        __syncthreads();
    };

    #pragma unroll 1
    for (int t = 0; t < 4; ++t) tick(t, TrueC{});
    #pragma unroll 1
    for (int t = 4; t < TT - 1; ++t) tick(t, FalseC{});     // branch-free steady state
    #pragma unroll 1
    for (int t = TT - 1; t < TT + 4; ++t) tick(t, TrueC{});

    // ------------- FC epilogue: h2(step 511) written at tick 515 -> buffer 1 ------
    if (tid < 16) {
        const int ms = tid >> 2, o = tid & 3;
        const h16* h2 = HT + 2 * 2048 + 1024;
        float acc = bfc[o];
        #pragma unroll 1
        for (int uu = 0; uu < 64; ++uu)
            acc += (float)h2[(uu >> 3) * 128 + (4 * ms) * 8 + (uu & 7)] * wfc[o * 64 + uu];
        out[(b4 + ms) * 4 + o] = acc;
    }
}

extern "C" void kernel_launch(void* const* d_in, const int* in_sizes, int n_in,
                              void* d_out, int out_size, void* d_ws, size_t ws_size,
                              hipStream_t stream) {
    const float* x    = (const float*)d_in[0];
    const float* wih0 = (const float*)d_in[1];
    const float* whh0 = (const float*)d_in[2];
    const float* bih0 = (const float*)d_in[3];
    const float* bhh0 = (const float*)d_in[4];
    const float* wih1 = (const float*)d_in[5];
    const float* whh1 = (const float*)d_in[6];
    const float* bih1 = (const float*)d_in[7];
    const float* bhh1 = (const float*)d_in[8];
    const float* wih2 = (const float*)d_in[9];
    const float* whh2 = (const float*)d_in[10];
    const float* bih2 = (const float*)d_in[11];
    const float* bhh2 = (const float*)d_in[12];
    const float* wfc  = (const float*)d_in[13];
    const float* bfc  = (const float*)d_in[14];
    float* out = (float*)d_out;

    lstm_mfma<<<dim3(NBLK), dim3(NTH), 0, stream>>>(
        x, wih0, whh0, bih0, bhh0, wih1, whh1, bih1, bhh1,
        wih2, whh2, bih2, bhh2, wfc, bfc, out);
}